// Round 20
// baseline (11.921 us; speedup 1.0000x reference)
//
#include <hip/hip_runtime.h>

#define NQ 10
#define NR 16              // amplitudes per lane (2^4)

// One WAVE per batch element: 64 lanes x 16 complex amps = 1024 amplitudes.
// Flat index k = lane*16 + r; bit c of k: c>=4 -> lane bit (c-4), c<4 -> reg bit c.
// r20 = r19 with the W#2 butterfly ELIMINATED via Walsh conjugation:
//   z[q] = psi† Z_Sq psi,  psi = W b  =>  z[q] = 1024 b† X_Sq b
//        = sum_k [br(k)br(k^Sq) + bi(k)bi(k^Sq)]   (imag parts cancel)
//   with b = D (W psi_init) / 32  (A scale 1/32; 1024/32^2 = 1).
//   S_q = (laneMask<<4)|regIdx from the r12/r13/r19 bench-verified table:
//   q: (ML,MR) = 0:(44,12) 1:(26,10) 2:(13,5) 3:(38,10) 4:(51,5)
//                5:(25,10) 6:(12,13) 7:(38,6) 8:(51,3)  9:(25,9)
//   7 distinct lane masks -> 7 batched shuffle stages (32 independent DS each).
//   * W psi_init built directly (j^-T product construction)   [r13-verified]
//   * phi via 16-pt WHT of lane-signed coefficients           [r13-verified]

__device__ __forceinline__ float xf(int i) { return __int_as_float(i); }
__device__ __forceinline__ int   fx(float f) { return __float_as_int(f); }

template<int M>
__device__ __forceinline__ float lane_xor(float v, int a32) {
    if constexpr (M == 1)        // quad_perm [1,0,3,2]
        return xf(__builtin_amdgcn_update_dpp(fx(v), fx(v), 0xB1, 0xF, 0xF, true));
    else if constexpr (M == 2)   // quad_perm [2,3,0,1]
        return xf(__builtin_amdgcn_update_dpp(fx(v), fx(v), 0x4E, 0xF, 0xF, true));
    else if constexpr (M == 8)   // row_ror:8
        return xf(__builtin_amdgcn_update_dpp(fx(v), fx(v), 0x128, 0xF, 0xF, true));
    else if constexpr (M == 4)   // ds_swizzle bit-mode xor 4
        return xf(__builtin_amdgcn_ds_swizzle(fx(v), 0x101F));
    else if constexpr (M == 16)  // ds_swizzle bit-mode xor 16
        return xf(__builtin_amdgcn_ds_swizzle(fx(v), 0x401F));
    else                         // M == 32: bpermute
        return xf(__builtin_amdgcn_ds_bpermute(a32, fx(v)));
}

__global__ __launch_bounds__(256, 2) void vql_kernel(
    const float* __restrict__ x,     // (B, NQ)
    const float* __restrict__ w,     // (NDEPTH, NQ)
    float* __restrict__ out)         // (B, NQ)
{
    const int lane = threadIdx.x & 63;
    const int b = blockIdx.x * 4 + (threadIdx.x >> 6);
    const int a32 = (lane ^ 32) << 2;

    // ---- per-batch angles (vectorized) ----
    const float2* xr = reinterpret_cast<const float2*>(x + b * NQ);
    const float2 x01 = xr[0], x23 = xr[1], x45 = xr[2], x67 = xr[3], x89 = xr[4];
    const float xa[NQ] = {0.5f * x01.x, 0.5f * x01.y, 0.5f * x23.x, 0.5f * x23.y,
                          0.5f * x45.x, 0.5f * x45.y, 0.5f * x67.x, 0.5f * x67.y,
                          0.5f * x89.x, 0.5f * x89.y};

    // ---- per-qubit Walsh factors of RX(w0q)RY(xq)|0>:  f'(t) = f(0) +- f(1) ----
    float F0r[NQ], F0i[NQ], F1r[NQ], F1i[NQ];
    #pragma unroll
    for (int q = 0; q < NQ; ++q) {
        float sy, cy, s, c;
        __sincosf(xa[q], &sy, &cy);
        __sincosf(0.5f * w[q], &s, &c);   // layer-0 weights
        const float v0r = c * cy,  v0i = -s * sy;
        const float v1r = c * sy,  v1i = -s * cy;
        F0r[q] = v0r + v1r;  F0i[q] = v0i + v1i;
        F1r[q] = v0r - v1r;  F1i[q] = v0i - v1i;
    }

    // ---- psi1 = W psi_init via j^-T bit formulas (r13-verified) ----
    const int L0 = lane & 1,        L1 = (lane >> 1) & 1, L2 = (lane >> 2) & 1;
    const int L3 = (lane >> 3) & 1, L4 = (lane >> 4) & 1, L5 = (lane >> 5) & 1;
    const int PL1 = L0 ^ L1, PL2 = PL1 ^ L2, PL3 = PL2 ^ L3, PL4 = PL3 ^ L4;
    const int g[7] = {PL4, PL4 ^ L5, PL3 ^ L5, PL2 ^ L5, PL1 ^ L5, L0 ^ L5, L5};
    #define SR_(q,bit) ((bit) ? F1r[q] : F0r[q])
    #define SI_(q,bit) ((bit) ? F1i[q] : F0i[q])

    float A_r[2], A_i[2];                 // prod q=0..6, for rp4 = 0/1
    #pragma unroll
    for (int t = 0; t < 2; ++t) {
        float ar = SR_(0, g[0] ^ t), ai = SI_(0, g[0] ^ t);
        #pragma unroll
        for (int q = 1; q < 7; ++q) {
            const float br = SR_(q, g[q] ^ t), bi = SI_(q, g[q] ^ t);
            const float nr = ar * br - ai * bi;
            const float ni = ar * bi + ai * br;
            ar = nr; ai = ni;
        }
        A_r[t] = ar * (1.0f / 32.0f);     // 1/32: z = 1024 b†Xb with b~1/1024
        A_i[t] = ai * (1.0f / 32.0f);     //       => use b̂=32b, z = b̂†Xb̂
    }
    float Gr[2][2], Gi[2][2];             // u8[t2]*u9[t1]
    #pragma unroll
    for (int t2 = 0; t2 < 2; ++t2)
        #pragma unroll
        for (int t1 = 0; t1 < 2; ++t1) {
            const float ar = SR_(8, t2 ^ L5), ai = SI_(8, t2 ^ L5);
            const float br = SR_(9, t1 ^ L5), bi = SI_(9, t1 ^ L5);
            Gr[t2][t1] = ar * br - ai * bi;
            Gi[t2][t1] = ar * bi + ai * br;
        }
    float Br_[2][2][2], Bi_[2][2][2];     // u7[t3]*G[t2][t1]
    #pragma unroll
    for (int t3 = 0; t3 < 2; ++t3)
        #pragma unroll
        for (int t2 = 0; t2 < 2; ++t2)
            #pragma unroll
            for (int t1 = 0; t1 < 2; ++t1) {
                const float ar = SR_(7, t3 ^ L5), ai = SI_(7, t3 ^ L5);
                Br_[t3][t2][t1] = ar * Gr[t2][t1] - ai * Gi[t2][t1];
                Bi_[t3][t2][t1] = ar * Gi[t2][t1] + ai * Gr[t2][t1];
            }
    float re[NR], im[NR];
    #pragma unroll
    for (int r = 0; r < NR; ++r) {
        const int r0 = r & 1, r1 = (r >> 1) & 1, r2 = (r >> 2) & 1, r3 = (r >> 3) & 1;
        const int p1 = r0, p2 = r0 ^ r1, p3 = p2 ^ r2, p4 = p3 ^ r3;
        const float br = Br_[p3][p2][p1], bi = Bi_[p3][p2][p1];
        re[r] = A_r[p4] * br - A_i[p4] * bi;
        im[r] = A_r[p4] * bi + A_i[p4] * br;
    }
    #undef SR_
    #undef SI_

    // ---- diagonal phases: phi[r] via 16-pt WHT of lane-signed coeffs ----
    float h1[NQ], h2[NQ], h3[NQ];
    #pragma unroll
    for (int q = 0; q < NQ; ++q) {
        h1[q] = 0.5f * w[NQ + q];
        h2[q] = 0.5f * w[2 * NQ + q];
        h3[q] = 0.5f * w[3 * NQ + q];
    }
    #define SG_(M) ((__builtin_popcount(lane & (M)) & 1) ? -1.f : 1.f)
    const float s1 = SG_(1),  s2 = SG_(2),  s3 = SG_(3),  s4 = SG_(4),  s5 = SG_(5);
    const float s6 = SG_(6),  s8 = SG_(8),  s10 = SG_(10), s12 = SG_(12);
    const float s16 = SG_(16), s20 = SG_(20), s24 = SG_(24), s32 = SG_(32);
    const float s40 = SG_(40), s48 = SG_(48);
    #undef SG_

    float C[NR];
    C[0]  = s32 * h1[0] + s16 * h1[1] + s8 * h1[2] + s4 * h1[3] + s2 * h1[4] + s1 * h1[5]
          + s48 * h2[0] + s24 * h2[1] + s12 * h2[2] + s6 * h2[3] + s3 * h2[4]
          + s40 * h3[0] + s20 * h3[1] + s10 * h3[2] + s5 * h3[3];
    C[8]  = h1[6] + s1 * h2[5] + s2 * h3[4];
    C[4]  = h1[7] + s1 * h3[5];
    C[2]  = h1[8] + s48 * h3[8];
    C[1]  = h1[9] + s48 * h2[9] + s24 * h3[9];
    C[12] = h2[6];
    C[6]  = h2[7];
    C[3]  = h2[8];
    C[10] = h3[6];
    C[5]  = h3[7];
    C[7] = 0.f; C[9] = 0.f; C[11] = 0.f; C[13] = 0.f; C[14] = 0.f; C[15] = 0.f;

    #pragma unroll
    for (int bset = 0; bset < 4; ++bset) {      // 16-pt WHT: C -> phi
        const int bb = 1 << bset;
        #pragma unroll
        for (int r = 0; r < NR; ++r) {
            if (!(r & bb)) {
                const float u = C[r], v = C[r | bb];
                C[r] = u + v;  C[r | bb] = u - v;
            }
        }
    }
    // apply e^{-i phi}: b = D psi1
    #pragma unroll
    for (int r = 0; r < NR; ++r) {
        float sp, cp;
        __sincosf(C[r], &sp, &cp);
        const float nr = re[r] * cp + im[r] * sp;
        const float ni = im[r] * cp - re[r] * sp;
        re[r] = nr; im[r] = ni;
    }

    // ---- X-string readout: z[q] = sum_k br(k)br(k^Sq) + bi(k)bi(k^Sq) ----
    const int a44 = (lane ^ 44) << 2;
    const int a38 = (lane ^ 38) << 2;
    const int a51 = (lane ^ 51) << 2;
    float z[NQ];

    {   // ML=44 (bpermute): q0, MR=12
        float sr[NR], si[NR];
        #pragma unroll
        for (int r = 0; r < NR; ++r) {
            sr[r] = xf(__builtin_amdgcn_ds_bpermute(a44, fx(re[r])));
            si[r] = xf(__builtin_amdgcn_ds_bpermute(a44, fx(im[r])));
        }
        float ar_ = 0.f, ai_ = 0.f;
        #pragma unroll
        for (int r = 0; r < NR; ++r) {
            ar_ = fmaf(re[r], sr[r ^ 12], ar_);
            ai_ = fmaf(im[r], si[r ^ 12], ai_);
        }
        z[0] = ar_ + ai_;
    }
    {   // ML=26 (swizzle 0x681F): q1, MR=10
        float sr[NR], si[NR];
        #pragma unroll
        for (int r = 0; r < NR; ++r) {
            sr[r] = xf(__builtin_amdgcn_ds_swizzle(fx(re[r]), 0x681F));
            si[r] = xf(__builtin_amdgcn_ds_swizzle(fx(im[r]), 0x681F));
        }
        float ar_ = 0.f, ai_ = 0.f;
        #pragma unroll
        for (int r = 0; r < NR; ++r) {
            ar_ = fmaf(re[r], sr[r ^ 10], ar_);
            ai_ = fmaf(im[r], si[r ^ 10], ai_);
        }
        z[1] = ar_ + ai_;
    }
    {   // ML=13 (swizzle 0x341F): q2, MR=5
        float sr[NR], si[NR];
        #pragma unroll
        for (int r = 0; r < NR; ++r) {
            sr[r] = xf(__builtin_amdgcn_ds_swizzle(fx(re[r]), 0x341F));
            si[r] = xf(__builtin_amdgcn_ds_swizzle(fx(im[r]), 0x341F));
        }
        float ar_ = 0.f, ai_ = 0.f;
        #pragma unroll
        for (int r = 0; r < NR; ++r) {
            ar_ = fmaf(re[r], sr[r ^ 5], ar_);
            ai_ = fmaf(im[r], si[r ^ 5], ai_);
        }
        z[2] = ar_ + ai_;
    }
    {   // ML=38 (bpermute): q3 MR=10, q7 MR=6
        float sr[NR], si[NR];
        #pragma unroll
        for (int r = 0; r < NR; ++r) {
            sr[r] = xf(__builtin_amdgcn_ds_bpermute(a38, fx(re[r])));
            si[r] = xf(__builtin_amdgcn_ds_bpermute(a38, fx(im[r])));
        }
        float a3r = 0.f, a3i = 0.f, a7r = 0.f, a7i = 0.f;
        #pragma unroll
        for (int r = 0; r < NR; ++r) {
            a3r = fmaf(re[r], sr[r ^ 10], a3r);
            a3i = fmaf(im[r], si[r ^ 10], a3i);
            a7r = fmaf(re[r], sr[r ^ 6], a7r);
            a7i = fmaf(im[r], si[r ^ 6], a7i);
        }
        z[3] = a3r + a3i;  z[7] = a7r + a7i;
    }
    {   // ML=51 (bpermute): q4 MR=5, q8 MR=3
        float sr[NR], si[NR];
        #pragma unroll
        for (int r = 0; r < NR; ++r) {
            sr[r] = xf(__builtin_amdgcn_ds_bpermute(a51, fx(re[r])));
            si[r] = xf(__builtin_amdgcn_ds_bpermute(a51, fx(im[r])));
        }
        float a4r = 0.f, a4i = 0.f, a8r = 0.f, a8i = 0.f;
        #pragma unroll
        for (int r = 0; r < NR; ++r) {
            a4r = fmaf(re[r], sr[r ^ 5], a4r);
            a4i = fmaf(im[r], si[r ^ 5], a4i);
            a8r = fmaf(re[r], sr[r ^ 3], a8r);
            a8i = fmaf(im[r], si[r ^ 3], a8i);
        }
        z[4] = a4r + a4i;  z[8] = a8r + a8i;
    }
    {   // ML=25 (swizzle 0x641F): q5 MR=10, q9 MR=9
        float sr[NR], si[NR];
        #pragma unroll
        for (int r = 0; r < NR; ++r) {
            sr[r] = xf(__builtin_amdgcn_ds_swizzle(fx(re[r]), 0x641F));
            si[r] = xf(__builtin_amdgcn_ds_swizzle(fx(im[r]), 0x641F));
        }
        float a5r = 0.f, a5i = 0.f, a9r = 0.f, a9i = 0.f;
        #pragma unroll
        for (int r = 0; r < NR; ++r) {
            a5r = fmaf(re[r], sr[r ^ 10], a5r);
            a5i = fmaf(im[r], si[r ^ 10], a5i);
            a9r = fmaf(re[r], sr[r ^ 9], a9r);
            a9i = fmaf(im[r], si[r ^ 9], a9i);
        }
        z[5] = a5r + a5i;  z[9] = a9r + a9i;
    }
    {   // ML=12 (swizzle 0x301F): q6, MR=13
        float sr[NR], si[NR];
        #pragma unroll
        for (int r = 0; r < NR; ++r) {
            sr[r] = xf(__builtin_amdgcn_ds_swizzle(fx(re[r]), 0x301F));
            si[r] = xf(__builtin_amdgcn_ds_swizzle(fx(im[r]), 0x301F));
        }
        float ar_ = 0.f, ai_ = 0.f;
        #pragma unroll
        for (int r = 0; r < NR; ++r) {
            ar_ = fmaf(re[r], sr[r ^ 13], ar_);
            ai_ = fmaf(im[r], si[r ^ 13], ai_);
        }
        z[6] = ar_ + ai_;
    }

    // ---- reduce each z over 64 lanes ----
    #pragma unroll
    for (int q = 0; q < NQ; ++q) {
        z[q] += lane_xor<1>(z[q], a32);
        z[q] += lane_xor<2>(z[q], a32);
        z[q] += lane_xor<4>(z[q], a32);
        z[q] += lane_xor<8>(z[q], a32);
        z[q] += lane_xor<16>(z[q], a32);
        z[q] += lane_xor<32>(z[q], a32);
    }
    if (lane == 0) {
        float2* op = reinterpret_cast<float2*>(out + b * NQ);
        op[0] = make_float2(z[0], z[1]);
        op[1] = make_float2(z[2], z[3]);
        op[2] = make_float2(z[4], z[5]);
        op[3] = make_float2(z[6], z[7]);
        op[4] = make_float2(z[8], z[9]);
    }
}

extern "C" void kernel_launch(void* const* d_in, const int* in_sizes, int n_in,
                              void* d_out, int out_size, void* d_ws, size_t ws_size,
                              hipStream_t stream) {
    const float* x = (const float*)d_in[0];        // (BATCH, NQ) fp32
    const float* w = (const float*)d_in[1];        // (NDEPTH, NQ) fp32
    float* out = (float*)d_out;                    // (BATCH, NQ) fp32
    const int B = in_sizes[0] / NQ;                // 2048 (divisible by 4)
    vql_kernel<<<B / 4, 256, 0, stream>>>(x, w, out);
}

// Round 21
// 11.058 us; speedup vs baseline: 1.0781x; 1.0781x over previous
//
#include <hip/hip_runtime.h>

#define NQ 10
#define NR 16              // amplitudes per lane (2^4)

// One WAVE per batch element: 64 lanes x 16 complex amps = 1024 amplitudes.
// Flat index k = lane*16 + r; bit c of k: c>=4 -> lane bit (c-4), c<4 -> reg bit c.
// r21 = r19 verbatim (11.05 us, best verified; r20's X-string readout regressed).
//   psi_final = W . diag(e^{-i phi}) . W . psi_init   (spectral form)
//   * W psi_init built directly (j^-T product construction)   [r13-verified]
//   * phi via 16-pt WHT of lane-signed coefficients           [r13-verified]
//   * W#2 butterfly + readout parity masks                    [r12/r13-verified]

__device__ __forceinline__ float xf(int i) { return __int_as_float(i); }
__device__ __forceinline__ int   fx(float f) { return __float_as_int(f); }

template<int M>
__device__ __forceinline__ float lane_xor(float v, int a32) {
    if constexpr (M == 1)        // quad_perm [1,0,3,2]
        return xf(__builtin_amdgcn_update_dpp(fx(v), fx(v), 0xB1, 0xF, 0xF, true));
    else if constexpr (M == 2)   // quad_perm [2,3,0,1]
        return xf(__builtin_amdgcn_update_dpp(fx(v), fx(v), 0x4E, 0xF, 0xF, true));
    else if constexpr (M == 8)   // row_ror:8
        return xf(__builtin_amdgcn_update_dpp(fx(v), fx(v), 0x128, 0xF, 0xF, true));
    else if constexpr (M == 4)   // ds_swizzle bit-mode xor 4
        return xf(__builtin_amdgcn_ds_swizzle(fx(v), 0x101F));
    else if constexpr (M == 16)  // ds_swizzle bit-mode xor 16
        return xf(__builtin_amdgcn_ds_swizzle(fx(v), 0x401F));
    else                         // M == 32: bpermute
        return xf(__builtin_amdgcn_ds_bpermute(a32, fx(v)));
}

__global__ __launch_bounds__(256, 2) void vql_kernel(
    const float* __restrict__ x,     // (B, NQ)
    const float* __restrict__ w,     // (NDEPTH, NQ)
    float* __restrict__ out)         // (B, NQ)
{
    const int lane = threadIdx.x & 63;
    const int b = blockIdx.x * 4 + (threadIdx.x >> 6);
    const int a32 = (lane ^ 32) << 2;

    // ---- per-batch angles (vectorized) ----
    const float2* xr = reinterpret_cast<const float2*>(x + b * NQ);
    const float2 x01 = xr[0], x23 = xr[1], x45 = xr[2], x67 = xr[3], x89 = xr[4];
    const float xa[NQ] = {0.5f * x01.x, 0.5f * x01.y, 0.5f * x23.x, 0.5f * x23.y,
                          0.5f * x45.x, 0.5f * x45.y, 0.5f * x67.x, 0.5f * x67.y,
                          0.5f * x89.x, 0.5f * x89.y};

    // ---- per-qubit Walsh factors of RX(w0q)RY(xq)|0>:  f'(t) = f(0) +- f(1) ----
    float F0r[NQ], F0i[NQ], F1r[NQ], F1i[NQ];
    #pragma unroll
    for (int q = 0; q < NQ; ++q) {
        float sy, cy, s, c;
        __sincosf(xa[q], &sy, &cy);
        __sincosf(0.5f * w[q], &s, &c);   // layer-0 weights
        const float v0r = c * cy,  v0i = -s * sy;
        const float v1r = c * sy,  v1i = -s * cy;
        F0r[q] = v0r + v1r;  F0i[q] = v0i + v1i;
        F1r[q] = v0r - v1r;  F1i[q] = v0i - v1i;
    }

    // ---- psi1 = W psi_init via j^-T bit formulas (r13-verified) ----
    const int L0 = lane & 1,        L1 = (lane >> 1) & 1, L2 = (lane >> 2) & 1;
    const int L3 = (lane >> 3) & 1, L4 = (lane >> 4) & 1, L5 = (lane >> 5) & 1;
    const int PL1 = L0 ^ L1, PL2 = PL1 ^ L2, PL3 = PL2 ^ L3, PL4 = PL3 ^ L4;
    const int g[7] = {PL4, PL4 ^ L5, PL3 ^ L5, PL2 ^ L5, PL1 ^ L5, L0 ^ L5, L5};
    #define SR_(q,bit) ((bit) ? F1r[q] : F0r[q])
    #define SI_(q,bit) ((bit) ? F1i[q] : F0i[q])

    float A_r[2], A_i[2];                 // prod q=0..6, for rp4 = 0/1
    #pragma unroll
    for (int t = 0; t < 2; ++t) {
        float ar = SR_(0, g[0] ^ t), ai = SI_(0, g[0] ^ t);
        #pragma unroll
        for (int q = 1; q < 7; ++q) {
            const float br = SR_(q, g[q] ^ t), bi = SI_(q, g[q] ^ t);
            const float nr = ar * br - ai * bi;
            const float ni = ar * bi + ai * br;
            ar = nr; ai = ni;
        }
        A_r[t] = ar * (1.0f / 1024.0f);   // fold W.W normalization
        A_i[t] = ai * (1.0f / 1024.0f);
    }
    float Gr[2][2], Gi[2][2];             // u8[t2]*u9[t1]
    #pragma unroll
    for (int t2 = 0; t2 < 2; ++t2)
        #pragma unroll
        for (int t1 = 0; t1 < 2; ++t1) {
            const float ar = SR_(8, t2 ^ L5), ai = SI_(8, t2 ^ L5);
            const float br = SR_(9, t1 ^ L5), bi = SI_(9, t1 ^ L5);
            Gr[t2][t1] = ar * br - ai * bi;
            Gi[t2][t1] = ar * bi + ai * br;
        }
    float Br_[2][2][2], Bi_[2][2][2];     // u7[t3]*G[t2][t1]
    #pragma unroll
    for (int t3 = 0; t3 < 2; ++t3)
        #pragma unroll
        for (int t2 = 0; t2 < 2; ++t2)
            #pragma unroll
            for (int t1 = 0; t1 < 2; ++t1) {
                const float ar = SR_(7, t3 ^ L5), ai = SI_(7, t3 ^ L5);
                Br_[t3][t2][t1] = ar * Gr[t2][t1] - ai * Gi[t2][t1];
                Bi_[t3][t2][t1] = ar * Gi[t2][t1] + ai * Gr[t2][t1];
            }
    float re[NR], im[NR];
    #pragma unroll
    for (int r = 0; r < NR; ++r) {
        const int r0 = r & 1, r1 = (r >> 1) & 1, r2 = (r >> 2) & 1, r3 = (r >> 3) & 1;
        const int p1 = r0, p2 = r0 ^ r1, p3 = p2 ^ r2, p4 = p3 ^ r3;
        const float br = Br_[p3][p2][p1], bi = Bi_[p3][p2][p1];
        re[r] = A_r[p4] * br - A_i[p4] * bi;
        im[r] = A_r[p4] * bi + A_i[p4] * br;
    }
    #undef SR_
    #undef SI_

    // ---- diagonal phases: phi[r] via 16-pt WHT of lane-signed coeffs ----
    float h1[NQ], h2[NQ], h3[NQ];
    #pragma unroll
    for (int q = 0; q < NQ; ++q) {
        h1[q] = 0.5f * w[NQ + q];
        h2[q] = 0.5f * w[2 * NQ + q];
        h3[q] = 0.5f * w[3 * NQ + q];
    }
    #define SG_(M) ((__builtin_popcount(lane & (M)) & 1) ? -1.f : 1.f)
    const float s1 = SG_(1),  s2 = SG_(2),  s3 = SG_(3),  s4 = SG_(4),  s5 = SG_(5);
    const float s6 = SG_(6),  s8 = SG_(8),  s10 = SG_(10), s12 = SG_(12);
    const float s16 = SG_(16), s20 = SG_(20), s24 = SG_(24), s32 = SG_(32);
    const float s40 = SG_(40), s48 = SG_(48);
    #undef SG_

    float C[NR];
    C[0]  = s32 * h1[0] + s16 * h1[1] + s8 * h1[2] + s4 * h1[3] + s2 * h1[4] + s1 * h1[5]
          + s48 * h2[0] + s24 * h2[1] + s12 * h2[2] + s6 * h2[3] + s3 * h2[4]
          + s40 * h3[0] + s20 * h3[1] + s10 * h3[2] + s5 * h3[3];
    C[8]  = h1[6] + s1 * h2[5] + s2 * h3[4];
    C[4]  = h1[7] + s1 * h3[5];
    C[2]  = h1[8] + s48 * h3[8];
    C[1]  = h1[9] + s48 * h2[9] + s24 * h3[9];
    C[12] = h2[6];
    C[6]  = h2[7];
    C[3]  = h2[8];
    C[10] = h3[6];
    C[5]  = h3[7];
    C[7] = 0.f; C[9] = 0.f; C[11] = 0.f; C[13] = 0.f; C[14] = 0.f; C[15] = 0.f;

    #pragma unroll
    for (int bset = 0; bset < 4; ++bset) {      // 16-pt WHT: C -> phi
        const int bb = 1 << bset;
        #pragma unroll
        for (int r = 0; r < NR; ++r) {
            if (!(r & bb)) {
                const float u = C[r], v = C[r | bb];
                C[r] = u + v;  C[r | bb] = u - v;
            }
        }
    }
    // apply e^{-i phi}
    #pragma unroll
    for (int r = 0; r < NR; ++r) {
        float sp, cp;
        __sincosf(C[r], &sp, &cp);
        const float nr = re[r] * cp + im[r] * sp;
        const float ni = im[r] * cp - re[r] * sp;
        re[r] = nr; im[r] = ni;
    }

    // ---- W#2: 10-level Walsh butterfly (r13 verbatim) ----
    #pragma unroll
    for (int bset = 0; bset < 4; ++bset) {      // reg levels (VALU only)
        const int bb = 1 << bset;
        #pragma unroll
        for (int r = 0; r < NR; ++r) {
            if (!(r & bb)) {
                float u = re[r], v = re[r | bb];
                re[r] = u + v;  re[r | bb] = u - v;
                u = im[r]; v = im[r | bb];
                im[r] = u + v;  im[r | bb] = u - v;
            }
        }
    }
    {
        const float sgA = (lane &  1) ? -1.f : 1.f;
        const float sgB = (lane &  2) ? -1.f : 1.f;
        const float sgC = (lane &  4) ? -1.f : 1.f;
        const float sgD = (lane &  8) ? -1.f : 1.f;
        const float sgE = (lane & 16) ? -1.f : 1.f;
        const float sgF = (lane & 32) ? -1.f : 1.f;
        #pragma unroll
        for (int r = 0; r < NR; ++r) {
            float p;
            p = lane_xor< 1>(re[r], a32); re[r] = fmaf(sgA, re[r], p);
            p = lane_xor< 1>(im[r], a32); im[r] = fmaf(sgA, im[r], p);
            p = lane_xor< 2>(re[r], a32); re[r] = fmaf(sgB, re[r], p);
            p = lane_xor< 2>(im[r], a32); im[r] = fmaf(sgB, im[r], p);
            p = lane_xor< 4>(re[r], a32); re[r] = fmaf(sgC, re[r], p);
            p = lane_xor< 4>(im[r], a32); im[r] = fmaf(sgC, im[r], p);
            p = lane_xor< 8>(re[r], a32); re[r] = fmaf(sgD, re[r], p);
            p = lane_xor< 8>(im[r], a32); im[r] = fmaf(sgD, im[r], p);
            p = lane_xor<16>(re[r], a32); re[r] = fmaf(sgE, re[r], p);
            p = lane_xor<16>(im[r], a32); im[r] = fmaf(sgE, im[r], p);
            p = lane_xor<32>(re[r], a32); re[r] = fmaf(sgF, re[r], p);
            p = lane_xor<32>(im[r], a32); im[r] = fmaf(sgF, im[r], p);
        }
    }

    // ---- readout: parity-mask observables (r12/r13 verbatim) ----
    float W[NR];
    #pragma unroll
    for (int r = 0; r < NR; ++r) W[r] = re[r] * re[r] + im[r] * im[r];
    #pragma unroll
    for (int bset = 0; bset < 4; ++bset) {
        const int bb = 1 << bset;
        #pragma unroll
        for (int r = 0; r < NR; ++r) {
            if (!(r & bb)) {
                const float u = W[r], v = W[r | bb];
                W[r] = u + v;  W[r | bb] = u - v;
            }
        }
    }
    const float sg44 = (__builtin_popcount(lane & 44) & 1) ? -1.f : 1.f;
    const float sg26 = (__builtin_popcount(lane & 26) & 1) ? -1.f : 1.f;
    const float sg13 = (__builtin_popcount(lane & 13) & 1) ? -1.f : 1.f;
    const float sg38 = (__builtin_popcount(lane & 38) & 1) ? -1.f : 1.f;
    const float sg51 = (__builtin_popcount(lane & 51) & 1) ? -1.f : 1.f;
    const float sg25 = (__builtin_popcount(lane & 25) & 1) ? -1.f : 1.f;
    const float sg12 = (__builtin_popcount(lane & 12) & 1) ? -1.f : 1.f;

    float z[NQ];
    z[0] = sg44 * W[12];
    z[1] = sg26 * W[10];
    z[2] = sg13 * W[ 5];
    z[3] = sg38 * W[10];
    z[4] = sg51 * W[ 5];
    z[5] = sg25 * W[10];
    z[6] = sg12 * W[13];
    z[7] = sg38 * W[ 6];
    z[8] = sg51 * W[ 3];
    z[9] = sg25 * W[ 9];

    #pragma unroll
    for (int q = 0; q < NQ; ++q) {
        z[q] += lane_xor<1>(z[q], a32);
        z[q] += lane_xor<2>(z[q], a32);
        z[q] += lane_xor<4>(z[q], a32);
        z[q] += lane_xor<8>(z[q], a32);
        z[q] += lane_xor<16>(z[q], a32);
        z[q] += lane_xor<32>(z[q], a32);
    }
    if (lane == 0) {
        float2* op = reinterpret_cast<float2*>(out + b * NQ);
        op[0] = make_float2(z[0], z[1]);
        op[1] = make_float2(z[2], z[3]);
        op[2] = make_float2(z[4], z[5]);
        op[3] = make_float2(z[6], z[7]);
        op[4] = make_float2(z[8], z[9]);
    }
}

extern "C" void kernel_launch(void* const* d_in, const int* in_sizes, int n_in,
                              void* d_out, int out_size, void* d_ws, size_t ws_size,
                              hipStream_t stream) {
    const float* x = (const float*)d_in[0];        // (BATCH, NQ) fp32
    const float* w = (const float*)d_in[1];        // (NDEPTH, NQ) fp32
    float* out = (float*)d_out;                    // (BATCH, NQ) fp32
    const int B = in_sizes[0] / NQ;                // 2048 (divisible by 4)
    vql_kernel<<<B / 4, 256, 0, stream>>>(x, w, out);
}